// Round 2
// baseline (163.912 us; speedup 1.0000x reference)
//
#include <hip/hip_runtime.h>
#include <hip/hip_bf16.h>

typedef __bf16 bf16;
typedef __attribute__((ext_vector_type(8))) __bf16 bf16x8;
typedef __attribute__((ext_vector_type(4))) __bf16 bf16x4;
typedef __attribute__((ext_vector_type(4))) float f32x4;

__device__ __forceinline__ void async_load16(const void* g, void* l) {
    __builtin_amdgcn_global_load_lds(
        (const __attribute__((address_space(1))) void*)g,
        (__attribute__((address_space(3))) void*)l, 16, 0, 0);
}

// ---------- kernel 1: per-block partial sum of |w| (deterministic tree) ----------
__global__ __launch_bounds__(256) void k_abs_part(const float* __restrict__ w, int n,
                                                  double* __restrict__ part) {
    __shared__ double sd[256];
    const int per_block = n / gridDim.x;
    const int base = blockIdx.x * per_block;
    double s = 0.0;
    for (int i = threadIdx.x; i < per_block; i += 256)
        s += (double)fabsf(w[base + i]);
    sd[threadIdx.x] = s;
    __syncthreads();
    for (int off = 128; off > 0; off >>= 1) {
        if (threadIdx.x < off) sd[threadIdx.x] += sd[threadIdx.x + off];
        __syncthreads();
    }
    if (threadIdx.x == 0) part[blockIdx.x] = sd[0];
}

// ---------- kernel 2: finalize delta = 0.7 * mean(|w|) ----------
__global__ __launch_bounds__(256) void k_delta(const double* __restrict__ part, int npart,
                                               int n, float* __restrict__ delta) {
    __shared__ double sd[256];
    double s = 0.0;
    for (int i = threadIdx.x; i < npart; i += 256) s += part[i];
    sd[threadIdx.x] = s;
    __syncthreads();
    for (int off = 128; off > 0; off >>= 1) {
        if (threadIdx.x < off) sd[threadIdx.x] += sd[threadIdx.x + off];
        __syncthreads();
    }
    if (threadIdx.x == 0) *delta = (float)(0.7 * sd[0] / (double)n);
}

// ---------- kernel 3: ternary-quantize weight to bf16 {-1,0,1}, natural [N][K] layout ----------
__global__ __launch_bounds__(256) void k_quant(const float* __restrict__ w,
                                               const float* __restrict__ dp,
                                               bf16* __restrict__ wt, int n4) {
    const float d = *dp;
    const int i = blockIdx.x * 256 + threadIdx.x;
    if (i >= n4) return;
    const float4 v = ((const float4*)w)[i];
    bf16x4 o;
    o[0] = (bf16)((v.x > d) ? 1.0f : (v.x < -d) ? -1.0f : 0.0f);
    o[1] = (bf16)((v.y > d) ? 1.0f : (v.y < -d) ? -1.0f : 0.0f);
    o[2] = (bf16)((v.z > d) ? 1.0f : (v.z < -d) ? -1.0f : 0.0f);
    o[3] = (bf16)((v.w > d) ? 1.0f : (v.w < -d) ? -1.0f : 0.0f);
    *(bf16x4*)(wt + (size_t)i * 4) = o;
}

// ---------- kernel 4: GEMM  C[m][n] = alpha * sum_k A[m][k]*Wt[n][k] + bias[n] ----------
// 128x128 tile, BK=64, 256 thr = 4 waves (2x2), 2-phase prefetch, XOR-swizzled LDS.
// A: fp32 global -> regs -> cvt bf16 -> swizzled ds_write_b128 (write+read both XOR'd).
// B: bf16 via global_load_lds (linear LDS dest) + inverse-swizzled GLOBAL source.
// Swizzle: 16B slot' = slot ^ (row & 7)  (row = 128 B = 8 slots -> spreads the
// 16-rows-same-slot fragment read across all 32 banks; residual 2-way = free).
__global__ __launch_bounds__(256, 2) void k_gemm(const float* __restrict__ A,
                                                 const bf16* __restrict__ Bw,
                                                 const float* __restrict__ alphap,
                                                 const float* __restrict__ bias,
                                                 float* __restrict__ C,
                                                 int M, int N, int K) {
    __shared__ __align__(16) bf16 As[2][128 * 64];
    __shared__ __align__(16) bf16 Bs[2][128 * 64];

    const int t    = threadIdx.x;
    const int lane = t & 63;
    const int wave = t >> 6;

    // XCD-chunked + n-fastest logical ordering: XCD x owns a contiguous m-range,
    // all n-tiles of an m-panel run on the same XCD -> A fetched once, L2-reused 8x.
    const int nbn = N >> 7;                       // 8 n-tiles
    const int cpx = gridDim.x >> 3;               // 256 per XCD (2048 % 8 == 0)
    const int lid = (blockIdx.x & 7) * cpx + (blockIdx.x >> 3);
    const int bn0 = (lid & (nbn - 1)) << 7;
    const int bm0 = (lid / nbn) << 7;

    const int wr = (wave >> 1) << 6;
    const int wc = (wave & 1) << 6;
    const int lr = lane & 15;
    const int hi = lane >> 4;                     // 0..3: k-slot group

    f32x4 acc[4][4] = {};

    // --- A staging geometry: 4 units/thread, each = 8 fp32 -> bf16x8 -> 1 ds_write_b128
    const int a_slot = t & 7;                     // 16B slot within row (8 fp32 src)
    const int a_row0 = t >> 3;                    // + u*32
    // --- B staging geometry: 4 global_load_lds issues, chunk c = j*256 + wave*64 + lane
    const int b_cl   = (wave << 6) | lane;        // 0..255
    const int b_row0 = b_cl >> 3;                 // + j*32
    const int b_slot = lane & 7;

    const int NT = K >> 6;                        // 16 K-steps
    int cur = 0;

    // ---------------- prologue: stage tile 0 ----------------
    {
        #pragma unroll
        for (int j = 0; j < 4; ++j) {
            const int row = (j << 5) + b_row0;
            const int ss  = b_slot ^ (row & 7);   // inverse-swizzled global source
            async_load16(Bw + (size_t)(bn0 + row) * K + (ss << 3),
                         (char*)&Bs[0][0] + (j << 12) + (wave << 10));
        }
        #pragma unroll
        for (int u = 0; u < 4; ++u) {
            const int row = (u << 5) + a_row0;
            const float4 v0 = *(const float4*)(A + (size_t)(bm0 + row) * K + (a_slot << 3));
            const float4 v1 = *(const float4*)(A + (size_t)(bm0 + row) * K + (a_slot << 3) + 4);
            bf16x8 h;
            h[0] = (bf16)v0.x; h[1] = (bf16)v0.y; h[2] = (bf16)v0.z; h[3] = (bf16)v0.w;
            h[4] = (bf16)v1.x; h[5] = (bf16)v1.y; h[6] = (bf16)v1.z; h[7] = (bf16)v1.w;
            *(bf16x8*)((char*)&As[0][0] + row * 128 + ((a_slot ^ (row & 7)) << 4)) = h;
        }
        __syncthreads();
    }

    // ---------------- main loop ----------------
    for (int kt = 0; kt < NT; ++kt) {
        const int nxt = cur ^ 1;
        const bool pf = (kt + 1) < NT;
        const int kn = (kt + 1) << 6;
        float4 av[8];

        if (pf) {
            // issue next-tile B loads (async, in flight across the MFMA phase)
            #pragma unroll
            for (int j = 0; j < 4; ++j) {
                const int row = (j << 5) + b_row0;
                const int ss  = b_slot ^ (row & 7);
                async_load16(Bw + (size_t)(bn0 + row) * K + kn + (ss << 3),
                             (char*)&Bs[nxt][0] + (j << 12) + (wave << 10));
            }
            // issue next-tile A loads into regs
            #pragma unroll
            for (int u = 0; u < 4; ++u) {
                const int row = (u << 5) + a_row0;
                av[2 * u]     = *(const float4*)(A + (size_t)(bm0 + row) * K + kn + (a_slot << 3));
                av[2 * u + 1] = *(const float4*)(A + (size_t)(bm0 + row) * K + kn + (a_slot << 3) + 4);
            }
        }

        // ---- compute current tile: 2 k-subs x (4x4 frags) x MFMA ----
        #pragma unroll
        for (int ksub = 0; ksub < 2; ++ksub) {
            const int ls = (ksub << 2) + hi;      // logical 16B slot 0..7
            bf16x8 af[4], bfm[4];
            #pragma unroll
            for (int m = 0; m < 4; ++m) {
                const int row = wr + (m << 4) + lr;
                af[m] = *(const bf16x8*)((char*)&As[cur][0] + row * 128 + ((ls ^ (row & 7)) << 4));
            }
            #pragma unroll
            for (int n = 0; n < 4; ++n) {
                const int row = wc + (n << 4) + lr;
                bfm[n] = *(const bf16x8*)((char*)&Bs[cur][0] + row * 128 + ((ls ^ (row & 7)) << 4));
            }
            #pragma unroll
            for (int m = 0; m < 4; ++m)
                #pragma unroll
                for (int n = 0; n < 4; ++n)
                    acc[m][n] = __builtin_amdgcn_mfma_f32_16x16x32_bf16(af[m], bfm[n], acc[m][n], 0, 0, 0);
        }

        if (pf) {
            // convert + swizzled write of next A tile
            #pragma unroll
            for (int u = 0; u < 4; ++u) {
                const int row = (u << 5) + a_row0;
                bf16x8 h;
                h[0] = (bf16)av[2*u].x;   h[1] = (bf16)av[2*u].y;
                h[2] = (bf16)av[2*u].z;   h[3] = (bf16)av[2*u].w;
                h[4] = (bf16)av[2*u+1].x; h[5] = (bf16)av[2*u+1].y;
                h[6] = (bf16)av[2*u+1].z; h[7] = (bf16)av[2*u+1].w;
                *(bf16x8*)((char*)&As[nxt][0] + row * 128 + ((a_slot ^ (row & 7)) << 4)) = h;
            }
        }
        __syncthreads();   // drains B gload_lds (vmcnt) + A ds_writes (lgkm)
        cur = nxt;
    }

    // ---------------- epilogue: alpha * acc + bias ----------------
    const float alpha = *alphap;
    float bv[4];
    #pragma unroll
    for (int n = 0; n < 4; ++n) bv[n] = bias[bn0 + wc + (n << 4) + lr];

    #pragma unroll
    for (int m = 0; m < 4; ++m) {
        #pragma unroll
        for (int n = 0; n < 4; ++n) {
            const int gcol = bn0 + wc + (n << 4) + lr;
            #pragma unroll
            for (int r = 0; r < 4; ++r) {
                const int grow = bm0 + wr + (m << 4) + (hi << 2) + r;
                C[(size_t)grow * N + gcol] = alpha * acc[m][n][r] + bv[n];
            }
        }
    }
}

extern "C" void kernel_launch(void* const* d_in, const int* in_sizes, int n_in,
                              void* d_out, int out_size, void* d_ws, size_t ws_size,
                              hipStream_t stream) {
    const float* x     = (const float*)d_in[0];
    const float* w     = (const float*)d_in[1];
    const float* alpha = (const float*)d_in[2];
    const float* bias  = (const float*)d_in[3];
    float* out = (float*)d_out;

    const int wn   = in_sizes[1];        // 1048576
    const int dout = in_sizes[3];        // 1024
    const int din  = wn / dout;          // 1024
    const int m    = in_sizes[0] / din;  // 32768

    char* ws = (char*)d_ws;
    float*  delta = (float*)ws;                 // [0,4)
    double* part  = (double*)(ws + 64);         // 256 doubles
    bf16*   wt    = (bf16*)(ws + 8192);         // 2 MiB ternary weights

    k_abs_part<<<256, 256, 0, stream>>>(w, wn, part);
    k_delta<<<1, 256, 0, stream>>>(part, 256, wn, delta);
    k_quant<<<(wn / 4 + 255) / 256, 256, 0, stream>>>(w, delta, wt, wn / 4);

    dim3 grid((m / 128) * (dout / 128));
    k_gemm<<<grid, 256, 0, stream>>>(x, wt, alpha, bias, out, m, dout, din);
}

// Round 3
// 128.619 us; speedup vs baseline: 1.2744x; 1.2744x over previous
//
#include <hip/hip_runtime.h>
#include <hip/hip_bf16.h>

typedef __bf16 bf16;
typedef __attribute__((ext_vector_type(8))) __bf16 bf16x8;
typedef __attribute__((ext_vector_type(4))) __bf16 bf16x4;
typedef __attribute__((ext_vector_type(4))) float f32x4;

#define BAR() __builtin_amdgcn_s_barrier()

__device__ __forceinline__ void async_load16(const void* g, void* l) {
    __builtin_amdgcn_global_load_lds(
        (const __attribute__((address_space(1))) void*)g,
        (__attribute__((address_space(3))) void*)l, 16, 0, 0);
}

// ---------- kernel 1: per-block partial sum of |w| (deterministic tree) ----------
__global__ __launch_bounds__(256) void k_abs_part(const float* __restrict__ w, int n,
                                                  double* __restrict__ part) {
    __shared__ double sd[256];
    const int per_block = n / gridDim.x;
    const int base = blockIdx.x * per_block;
    double s = 0.0;
    for (int i = threadIdx.x; i < per_block; i += 256)
        s += (double)fabsf(w[base + i]);
    sd[threadIdx.x] = s;
    __syncthreads();
    for (int off = 128; off > 0; off >>= 1) {
        if (threadIdx.x < off) sd[threadIdx.x] += sd[threadIdx.x + off];
        __syncthreads();
    }
    if (threadIdx.x == 0) part[blockIdx.x] = sd[0];
}

// ---------- kernel 2: finalize delta = 0.7 * mean(|w|) ----------
__global__ __launch_bounds__(256) void k_delta(const double* __restrict__ part, int npart,
                                               int n, float* __restrict__ delta) {
    __shared__ double sd[256];
    double s = 0.0;
    for (int i = threadIdx.x; i < npart; i += 256) s += part[i];
    sd[threadIdx.x] = s;
    __syncthreads();
    for (int off = 128; off > 0; off >>= 1) {
        if (threadIdx.x < off) sd[threadIdx.x] += sd[threadIdx.x + off];
        __syncthreads();
    }
    if (threadIdx.x == 0) *delta = (float)(0.7 * sd[0] / (double)n);
}

// ---------- kernel 3: ternary-quantize weight to bf16 {-1,0,1} ----------
__global__ __launch_bounds__(256) void k_quant(const float* __restrict__ w,
                                               const float* __restrict__ dp,
                                               bf16* __restrict__ wt, int n4) {
    const float d = *dp;
    const int i = blockIdx.x * 256 + threadIdx.x;
    if (i >= n4) return;
    const float4 v = ((const float4*)w)[i];
    bf16x4 o;
    o[0] = (bf16)((v.x > d) ? 1.0f : (v.x < -d) ? -1.0f : 0.0f);
    o[1] = (bf16)((v.y > d) ? 1.0f : (v.y < -d) ? -1.0f : 0.0f);
    o[2] = (bf16)((v.z > d) ? 1.0f : (v.z < -d) ? -1.0f : 0.0f);
    o[3] = (bf16)((v.w > d) ? 1.0f : (v.w < -d) ? -1.0f : 0.0f);
    *(bf16x4*)(wt + (size_t)i * 4) = o;
}

// ---------- kernel 3b: convert A fp32 -> bf16 (streaming, vectorized) ----------
__global__ __launch_bounds__(256) void k_convA(const float* __restrict__ x,
                                               bf16* __restrict__ y, int n8) {
    const int stride = gridDim.x * 256;
    for (int i = blockIdx.x * 256 + threadIdx.x; i < n8; i += stride) {
        const float4 a = ((const float4*)x)[2 * i];
        const float4 b = ((const float4*)x)[2 * i + 1];
        bf16x8 h;
        h[0] = (bf16)a.x; h[1] = (bf16)a.y; h[2] = (bf16)a.z; h[3] = (bf16)a.w;
        h[4] = (bf16)b.x; h[5] = (bf16)b.y; h[6] = (bf16)b.z; h[7] = (bf16)b.w;
        ((bf16x8*)y)[i] = h;
    }
}

// ---------- helper: stage one 128x64 bf16 half-tile via global_load_lds ----------
// LDS dest linear (gload_lds requirement); swizzle achieved by inverse-permuting
// the GLOBAL source 16B-slot: s = (c&7) ^ (rowp&7). 512 thr x 2 loads = 1024 chunks.
__device__ __forceinline__ void stage_half(const bf16* __restrict__ srch, int K, int kt,
                                           char* dst, int t) {
    #pragma unroll
    for (int r = 0; r < 2; ++r) {
        const int c  = (r << 9) + t;
        const int rp = c >> 3;
        const int s  = (c & 7) ^ ((t >> 3) & 7);   // (rp&7) == ((t>>3)&7) since 64%8==0
        async_load16(srch + (size_t)rp * K + (kt << 6) + (s << 3), dst + (c << 4));
    }
}

// ---------- kernel 4: 256x256 8-phase bf16 GEMM (T2+T3+T4+T5) ----------
// C[m][n] = alpha * sum_k A[m][k]*Wt[n][k] + bias[n].  512 thr = 8 waves (2M x 4N),
// BK=64, LDS 128KB = 2 parity x {A,B} x 2 half(128x64).  Counted vmcnt(4) at P0/P4.
// Staging order (liveness-derived): P0:HA0(ktB) P1:HA1(ktB) P2:HB0(ktA+2) P3:HB1(ktA+2)
// P4:HA0(ktA+2) P5:HA1(ktA+2) P6:HB0(ktB+2) P7:HB1(ktB+2).  Final iter wraps stage
// kt to 0/1 (valid addrs, dead data) so loop body + vmcnt counts stay uniform.
__global__ __launch_bounds__(512, 2) void k_gemm8(const bf16* __restrict__ A,
                                                  const bf16* __restrict__ Bw,
                                                  const float* __restrict__ alphap,
                                                  const float* __restrict__ bias,
                                                  float* __restrict__ C,
                                                  int M, int N, int K) {
    __shared__ __align__(16) char lds[2][2][2][16384];  // [parity][op A=0/B=1][half][16KB]

    const int t    = threadIdx.x;
    const int lane = t & 63;
    const int w    = t >> 6;
    const int wm   = w >> 2;          // 0/1: rows wm*128..+127
    const int wn   = w & 3;           // 0..3: cols wn*64..+63
    const int lr   = lane & 15;
    const int hi   = lane >> 4;

    // XCD-chunked, n-fastest: each XCD owns contiguous m-panels; A L2-reused 4x.
    const int nbn = N >> 8;                       // 4 n-tiles
    const int cpx = gridDim.x >> 3;
    const int lid = (blockIdx.x & 7) * cpx + (blockIdx.x >> 3);
    const int bn0 = (lid % nbn) << 8;
    const int bm0 = (lid / nbn) << 8;

    const bf16* Asrc[2] = { A  + (size_t)bm0 * K,  A  + (size_t)(bm0 + 128) * K };
    const bf16* Bsrc[2] = { Bw + (size_t)bn0 * K,  Bw + (size_t)(bn0 + 128) * K };

    f32x4 acc[8][4] = {};
    bf16x8 afq[4][2], bfA[2][2], bfB[2][2];

    // per-thread constant swizzled slot offsets: slot ks*4+hi, XOR row&7 == lr&7
    const int x0 = ((hi ^ (lr & 7)) << 4);
    const int x1 = (((4 + hi) ^ (lr & 7)) << 4);

#define LDA_Q(MQ, PAR) do { \
    const char* _b = &lds[PAR][0][wm][0]; \
    _Pragma("unroll") \
    for (int m = 0; m < 4; ++m) { \
        const int _r = ((MQ) << 6) + (m << 4) + lr; \
        afq[m][0] = *(const bf16x8*)(_b + _r * 128 + x0); \
        afq[m][1] = *(const bf16x8*)(_b + _r * 128 + x1); \
    } \
} while (0)

#define LDB_Q(DST, NQ, PAR) do { \
    const char* _b = &lds[PAR][1][wn >> 1][0]; \
    _Pragma("unroll") \
    for (int n = 0; n < 2; ++n) { \
        const int _r = ((wn & 1) << 6) + ((((NQ) << 1) + n) << 4) + lr; \
        DST[n][0] = *(const bf16x8*)(_b + _r * 128 + x0); \
        DST[n][1] = *(const bf16x8*)(_b + _r * 128 + x1); \
    } \
} while (0)

#define MF_Q(MQ, NQ, BF) do { \
    __builtin_amdgcn_s_setprio(1); \
    _Pragma("unroll") \
    for (int ks = 0; ks < 2; ++ks) \
        _Pragma("unroll") \
        for (int m = 0; m < 4; ++m) { \
            acc[((MQ)<<2)+m][((NQ)<<1)+0] = __builtin_amdgcn_mfma_f32_16x16x32_bf16(afq[m][ks], BF[0][ks], acc[((MQ)<<2)+m][((NQ)<<1)+0], 0, 0, 0); \
            acc[((MQ)<<2)+m][((NQ)<<1)+1] = __builtin_amdgcn_mfma_f32_16x16x32_bf16(afq[m][ks], BF[1][ks], acc[((MQ)<<2)+m][((NQ)<<1)+1], 0, 0, 0); \
        } \
    __builtin_amdgcn_s_setprio(0); \
} while (0)

#define VMCNT4() asm volatile("s_waitcnt vmcnt(4)" ::: "memory")

    // ---------------- prologue: kt0 all 4 halves, then kt1 B halves ----------------
    stage_half(Bsrc[0], K, 0, &lds[0][1][0][0], t);
    stage_half(Bsrc[1], K, 0, &lds[0][1][1][0], t);
    stage_half(Asrc[0], K, 0, &lds[0][0][0][0], t);
    stage_half(Asrc[1], K, 0, &lds[0][0][1][0], t);
    stage_half(Bsrc[0], K, 1, &lds[1][1][0][0], t);
    stage_half(Bsrc[1], K, 1, &lds[1][1][1][0], t);
    asm volatile("s_waitcnt vmcnt(0)" ::: "memory");
    BAR();

    const int NI = K >> 7;   // 8 iterations, 2 K-tiles each
    for (int i = 0; i < NI; ++i) {
        const int  ktB  = 2 * i + 1;
        const bool last = (i == NI - 1);
        const int  kA2  = last ? 0 : 2 * i + 2;   // wrap: valid addr, dead data
        const int  kB2  = last ? 1 : 2 * i + 3;

        // P0: quadrant (0,0) of ktA (parity 0)
        VMCNT4();
        LDA_Q(0, 0); LDB_Q(bfA, 0, 0);
        stage_half(Asrc[0], K, ktB, &lds[1][0][0][0], t);
        BAR(); MF_Q(0, 0, bfA); BAR();
        // P1: (0,1)
        LDB_Q(bfB, 1, 0);
        stage_half(Asrc[1], K, ktB, &lds[1][0][1][0], t);
        BAR(); MF_Q(0, 1, bfB); BAR();
        // P2: (1,1)
        LDA_Q(1, 0);
        stage_half(Bsrc[0], K, kA2, &lds[0][1][0][0], t);
        BAR(); MF_Q(1, 1, bfB); BAR();
        // P3: (1,0)
        stage_half(Bsrc[1], K, kA2, &lds[0][1][1][0], t);
        BAR(); MF_Q(1, 0, bfA); BAR();

        // P4: quadrant (0,0) of ktB (parity 1)
        VMCNT4();
        LDA_Q(0, 1); LDB_Q(bfA, 0, 1);
        stage_half(Asrc[0], K, kA2, &lds[0][0][0][0], t);
        BAR(); MF_Q(0, 0, bfA); BAR();
        // P5: (0,1)
        LDB_Q(bfB, 1, 1);
        stage_half(Asrc[1], K, kA2, &lds[0][0][1][0], t);
        BAR(); MF_Q(0, 1, bfB); BAR();
        // P6: (1,1)
        LDA_Q(1, 1);
        stage_half(Bsrc[0], K, kB2, &lds[1][1][0][0], t);
        BAR(); MF_Q(1, 1, bfB); BAR();
        // P7: (1,0)
        stage_half(Bsrc[1], K, kB2, &lds[1][1][1][0], t);
        BAR(); MF_Q(1, 0, bfA); BAR();
    }

    // ---------------- epilogue ----------------
    const float alpha = *alphap;
    float bv[4];
    #pragma unroll
    for (int nf = 0; nf < 4; ++nf) bv[nf] = bias[bn0 + (wn << 6) + (nf << 4) + lr];

    #pragma unroll
    for (int mf = 0; mf < 8; ++mf) {
        const int grow = bm0 + (wm << 7) + (mf << 4) + (hi << 2);
        #pragma unroll
        for (int nf = 0; nf < 4; ++nf) {
            const int gcol = bn0 + (wn << 6) + (nf << 4) + lr;
            #pragma unroll
            for (int r = 0; r < 4; ++r)
                C[(size_t)(grow + r) * N + gcol] = alpha * acc[mf][nf][r] + bv[nf];
        }
    }
#undef LDA_Q
#undef LDB_Q
#undef MF_Q
#undef VMCNT4
}

// ---------- fallback GEMM (round-1 proven): fp32 A staged in-kernel ----------
__global__ __launch_bounds__(256) void k_gemm_fb(const float* __restrict__ A,
                                                 const bf16* __restrict__ Bw,
                                                 const float* __restrict__ alphap,
                                                 const float* __restrict__ bias,
                                                 float* __restrict__ C,
                                                 int M, int N, int K) {
    __shared__ bf16 As[128 * 32];
    __shared__ bf16 Bs[128 * 32];
    const int t = threadIdx.x, lane = t & 63, wave = t >> 6;
    const int nbm = M >> 7;
    const int bm0 = (blockIdx.x % nbm) << 7;
    const int bn0 = (blockIdx.x / nbm) << 7;
    const int wr = (wave >> 1) << 6, wc = (wave & 1) << 6;
    f32x4 acc[4][4] = {};
    const int lr = lane & 15, lk = (lane >> 4) << 3;
    for (int k0 = 0; k0 < K; k0 += 32) {
        #pragma unroll
        for (int j = 0; j < 2; ++j) {
            const int c = t + j * 256;
            async_load16(Bw + (size_t)(bn0 + (c >> 2)) * K + k0 + ((c & 3) << 3),
                         (char*)Bs + j * 4096 + wave * 1024);
        }
        #pragma unroll
        for (int i = 0; i < 4; ++i) {
            const int idx = t + i * 256;
            const int row = idx >> 3, c4 = (idx & 7) << 2;
            const float4 v = *(const float4*)(A + (size_t)(bm0 + row) * K + k0 + c4);
            bf16x4 h;
            h[0] = (bf16)v.x; h[1] = (bf16)v.y; h[2] = (bf16)v.z; h[3] = (bf16)v.w;
            *(bf16x4*)(As + row * 32 + c4) = h;
        }
        __syncthreads();
        bf16x8 af[4], bfr[4];
        #pragma unroll
        for (int m = 0; m < 4; ++m) af[m] = *(const bf16x8*)(As + (wr + m * 16 + lr) * 32 + lk);
        #pragma unroll
        for (int n = 0; n < 4; ++n) bfr[n] = *(const bf16x8*)(Bs + (wc + n * 16 + lr) * 32 + lk);
        #pragma unroll
        for (int m = 0; m < 4; ++m)
            #pragma unroll
            for (int n = 0; n < 4; ++n)
                acc[m][n] = __builtin_amdgcn_mfma_f32_16x16x32_bf16(af[m], bfr[n], acc[m][n], 0, 0, 0);
        __syncthreads();
    }
    const float alpha = *alphap;
    #pragma unroll
    for (int m = 0; m < 4; ++m)
        #pragma unroll
        for (int n = 0; n < 4; ++n) {
            const int gcol = bn0 + wc + n * 16 + lr;
            const float bv = bias[gcol];
            #pragma unroll
            for (int r = 0; r < 4; ++r) {
                const int grow = bm0 + wr + m * 16 + ((lane >> 4) << 2) + r;
                C[(size_t)grow * N + gcol] = alpha * acc[m][n][r] + bv;
            }
        }
}

extern "C" void kernel_launch(void* const* d_in, const int* in_sizes, int n_in,
                              void* d_out, int out_size, void* d_ws, size_t ws_size,
                              hipStream_t stream) {
    const float* x     = (const float*)d_in[0];
    const float* wgt   = (const float*)d_in[1];
    const float* alpha = (const float*)d_in[2];
    const float* bias  = (const float*)d_in[3];
    float* out = (float*)d_out;

    const int wn   = in_sizes[1];        // 1048576
    const int dout = in_sizes[3];        // 1024
    const int din  = wn / dout;          // 1024
    const int m    = in_sizes[0] / din;  // 32768

    char* ws = (char*)d_ws;
    float*  delta = (float*)ws;                  // [0,4)
    double* part  = (double*)(ws + 64);          // 256 doubles
    bf16*   wt    = (bf16*)(ws + 8192);          // 2 MiB ternary weights
    bf16*   abf   = (bf16*)(ws + (4u << 20));    // 64 MiB bf16 A

    k_abs_part<<<256, 256, 0, stream>>>(wgt, wn, part);
    k_delta<<<1, 256, 0, stream>>>(part, 256, wn, delta);
    k_quant<<<(wn / 4 + 255) / 256, 256, 0, stream>>>(wgt, delta, wt, wn / 4);

    const size_t need = (4u << 20) + (size_t)in_sizes[0] * 2;
    if (ws_size >= need && (m % 256) == 0 && (dout % 256) == 0 && (din % 128) == 0) {
        k_convA<<<2048, 256, 0, stream>>>(x, abf, in_sizes[0] / 8);
        dim3 grid((m / 256) * (dout / 256));
        k_gemm8<<<grid, 512, 0, stream>>>(abf, wt, alpha, bias, out, m, dout, din);
    } else {
        dim3 grid((m / 128) * (dout / 128));
        k_gemm_fb<<<grid, 256, 0, stream>>>(x, wt, alpha, bias, out, m, dout, din);
    }
}